// Round 19
// baseline (461.225 us; speedup 1.0000x reference)
//
#include <hip/hip_runtime.h>

typedef __attribute__((ext_vector_type(4))) float f32x4;
typedef __attribute__((ext_vector_type(8))) __bf16 bf16x8;
typedef __attribute__((ext_vector_type(8))) unsigned short u16x8;
typedef __attribute__((ext_vector_type(4))) unsigned short u16x4;
typedef __attribute__((ext_vector_type(4))) short s16x4;
typedef unsigned short ushort_t;

// ---------- bf16 helpers ----------
__device__ __forceinline__ unsigned short f2bf(float x) {
  unsigned u = __builtin_bit_cast(unsigned, x);
  u += 0x7fffu + ((u >> 16) & 1u);
  return (unsigned short)(u >> 16);
}
__device__ __forceinline__ float bf2f(unsigned short h) {
  unsigned u = ((unsigned)h) << 16;
  return __builtin_bit_cast(float, u);
}
__device__ __forceinline__ short f2bf_n(float x) {
  return __builtin_bit_cast(short, (__bf16)x);
}

// ---------- async global->LDS (16B per lane) ----------
__device__ __forceinline__ void gload_lds16(const void* g, void* l) {
  __builtin_amdgcn_global_load_lds(
      (const __attribute__((address_space(1))) unsigned int*)g,
      (__attribute__((address_space(3))) unsigned int*)l, 16, 0, 0);
}

// ---------- fused all-weights+X f32->bf16 (one dispatch, exact ranges) ----------
__global__ __launch_bounds__(256) void k_xw_to_bf16(
    const float* __restrict__ X, const float* __restrict__ Wq,
    const float* __restrict__ Wk, const float* __restrict__ Wv,
    const float* __restrict__ Wo,
    ushort_t* __restrict__ dX, ushort_t* __restrict__ dWq,
    ushort_t* __restrict__ dWk, ushort_t* __restrict__ dWv,
    ushort_t* __restrict__ dWo) {
  const int b = blockIdx.x;
  const float* src;
  ushort_t* dst;
  int i;
  if (b < 8192)       { src = X;  dst = dX;  i = b * 256 + threadIdx.x; }
  else if (b < 16384) { src = Wq; dst = dWq; i = (b - 8192) * 256 + threadIdx.x; }
  else if (b < 18432) { src = Wk; dst = dWk; i = (b - 16384) * 256 + threadIdx.x; }
  else if (b < 19968) { src = Wv; dst = dWv; i = (b - 18432) * 256 + threadIdx.x; }
  else                { src = Wo; dst = dWo; i = (b - 19968) * 256 + threadIdx.x; }
  float4 a = ((const float4*)src)[i * 2 + 0];
  float4 c = ((const float4*)src)[i * 2 + 1];
  u16x8 o;
  o[0] = f2bf(a.x); o[1] = f2bf(a.y); o[2] = f2bf(a.z); o[3] = f2bf(a.w);
  o[4] = f2bf(c.x); o[5] = f2bf(c.y); o[6] = f2bf(c.z); o[7] = f2bf(c.w);
  ((u16x8*)dst)[i] = o;
}

// ---------- bf16 B^T GEMM: C[M,N] = A[M,K] * B[N,K]^T (m97 structure) ----------
// launch_bounds (256,4): R14 verified VGPR 64, occupancy 31%, MfmaUtil 48.
// ROPE=1 (QKV): rotary fused in epilogue.
template <int OUT_BF16, int ROPE>
__global__ __launch_bounds__(256, 4) void k_gemm_bt(
    const ushort_t* __restrict__ A, const ushort_t* __restrict__ B,
    void* __restrict__ C, int K, int lda, int ldb, int ldc,
    const int* __restrict__ pos_ids) {
  __shared__ ushort_t lA[128 * 64];
  __shared__ ushort_t lB[128 * 64];
  const int t = threadIdx.x;
  const int ln = t & 63, w = t >> 6;
  const int fr = ln & 15, fg = ln >> 4;
  const int m0 = blockIdx.x * 128, n0 = blockIdx.y * 128;
  const int wr = (w >> 1) * 64, wc = (w & 1) * 64;

  const int srow = t >> 3;
  const int scol = ((((t & 7) * 16) ^ ((srow & 7) << 4)) >> 1);
  const ushort_t* pA = A + (srow + m0) * lda + scol;
  const ushort_t* pB = B + (srow + n0) * ldb + scol;
  char* lAb = (char*)lA + (w << 10);
  char* lBb = (char*)lB + (w << 10);

  f32x4 acc[4][4] = {};

  for (int k0 = 0; k0 < K; k0 += 64) {
    __syncthreads();
#pragma unroll
    for (int i = 0; i < 4; ++i) {
      gload_lds16(pA + i * 32 * lda + k0, lAb + i * 4096);
      gload_lds16(pB + i * 32 * ldb + k0, lBb + i * 4096);
    }
    __syncthreads();
#pragma unroll
    for (int kh = 0; kh < 2; ++kh) {
      bf16x8 af[4], bfv[4];
#pragma unroll
      for (int m = 0; m < 4; ++m) {
        int row = wr + m * 16 + fr;
        af[m] = *(const bf16x8*)((const char*)lA + row * 128 +
                                 ((kh * 64 + fg * 16) ^ ((row & 7) << 4)));
      }
#pragma unroll
      for (int n = 0; n < 4; ++n) {
        int row = wc + n * 16 + fr;
        bfv[n] = *(const bf16x8*)((const char*)lB + row * 128 +
                                  ((kh * 64 + fg * 16) ^ ((row & 7) << 4)));
      }
#pragma unroll
      for (int m = 0; m < 4; ++m)
#pragma unroll
        for (int n = 0; n < 4; ++n)
          acc[m][n] = __builtin_amdgcn_mfma_f32_16x16x32_bf16(
              af[m], bfv[n], acc[m][n], 0, 0, 0);
    }
  }

  // ---- fused RoPE (QKV epilogue only; wave-uniform predicate) ----
  if (ROPE) {
    if (n0 < 5120 && wc == 0) {
#pragma unroll
      for (int n = 0; n < 2; ++n) {
        const float fi = (float)(n * 16 + fr);          // freq index 0..31
        const float inv = exp2f(-fi * (13.287712379549449f / 32.0f));
#pragma unroll
        for (int m = 0; m < 4; ++m) {
          const int row = m0 + wr + m * 16 + fg * 4;
#pragma unroll
          for (int j = 0; j < 4; ++j) {
            const float ang = (float)pos_ids[row + j] * inv;
            float sn, cs;
            __sincosf(ang, &sn, &cs);
            const float x1 = acc[m][n][j], x2 = acc[m][n + 2][j];
            acc[m][n][j]     = x1 * cs - x2 * sn;
            acc[m][n + 2][j] = x2 * cs + x1 * sn;
          }
        }
      }
    }
  }

#pragma unroll
  for (int m = 0; m < 4; ++m)
#pragma unroll
    for (int n = 0; n < 4; ++n) {
      int row = m0 + wr + m * 16 + fg * 4;
      int col = n0 + wc + n * 16 + fr;
#pragma unroll
      for (int j = 0; j < 4; ++j) {
        if (OUT_BF16)
          ((ushort_t*)C)[(size_t)(row + j) * ldc + col] = f2bf(acc[m][n][j]);
        else
          ((float*)C)[(size_t)(row + j) * ldc + col] = acc[m][n][j];
      }
    }
}

// ---------- causal GQA flash attention (S^T / O^T, reg-resident P) ----------
// KVBLK=64 with K/V LDS DOUBLE-BUFFER (2x16KB K + 2x12.1KB V = 56.8KB ->
// 2 blocks/CU retained). Per tile: issue K(kt+1)->buf^1, ds_write V(kt+1)
// ->buf^1 (reg-dependency waited by compiler), issue V(kt+2) loads, compute
// buf, then ONE tail barrier with counted vmcnt(4) (drains the older K
// gloads; V(kt+2) stays in flight). Same barrier rate as R15/R18 but the K
// latency is prefetched a tile ahead and V-writes overlap compute.
// lV pad = 97 slots (776B stride = 2-bank step -> 2-way write conflicts).
// Fixed-shift softmax (exact); l reduction deferred to epilogue.
__global__ __launch_bounds__(512, 2) void k_attn(
    const ushort_t* __restrict__ QKV, ushort_t* __restrict__ O) {
  __shared__ ushort_t lK[2][64 * 128];    // XOR-swizzled rows of 256B
  __shared__ ushort_t lV[2][16 * 97 * 4]; // quad layout, padded row stride

  const int t = threadIdx.x, ln = t & 63, w = t >> 6;
  const int fr = ln & 15, fg = ln >> 4;
  const int h = blockIdx.y, b = blockIdx.z;
  const int qt = b ? (7 - (int)blockIdx.x) : (int)blockIdx.x;
  const int hk = h >> 2;
  const int q0 = qt * 256 + w * 32;
  const int tb = b * 2048;

  // Q B-frags: lane (fr,fg) holds Q[q0+rq*16+fr][kb*32+fg*8 ..+7]
  bf16x8 qf[2][4];
#pragma unroll
  for (int rq = 0; rq < 2; ++rq)
#pragma unroll
    for (int kb = 0; kb < 4; ++kb)
      qf[rq][kb] = *(const bf16x8*)(QKV +
                    (size_t)(tb + q0 + rq * 16 + fr) * 5888 + h * 128 +
                    kb * 32 + fg * 8);

  f32x4 oacc[6][2] = {};            // O^T: c = c6*16+fg*4+j, q = rq*16+fr
  float lreg[2] = {0.f, 0.f};       // per-lane partial of l (reduced at end)

  const int krow = t >> 4;                    // 0..31 (2 issues x 32 rows)
  const int kse = ((((t & 15) * 16) ^ (((t >> 4) & 7) << 4)) >> 1);
  const int k4s = t / 12, c8s = t % 12;       // V staging unit (t<192)

  const float sc = 0.088388347648318447f;     // 1/sqrt(128)
  const float l2e = 1.4426950408889634f;
  const float scl2e = sc * l2e;
  const float MB = 16.0f * l2e;               // fixed softmax shift (exact)

  const ushort_t* pVb =
      QKV + (size_t)(tb + k4s * 4) * 5888 + 5120 + hk * 96 + c8s * 8;
  const ushort_t* pKb =
      QKV + (size_t)(tb + krow) * 5888 + 4096 + hk * 128 + kse;

  const int nkt = qt * 4 + 4;                 // 64-wide tiles (nkt >= 4)
  u16x8 vrow[4];

  // ---- prologue: V(0)+K(0) -> buf0; V(1) in flight ----
  if (t < 192) {
#pragma unroll
    for (int kr = 0; kr < 4; ++kr)
      vrow[kr] = *(const u16x8*)(pVb + (size_t)kr * 5888);
  }
#pragma unroll
  for (int i = 0; i < 2; ++i)
    gload_lds16(pKb + (size_t)i * 32 * 5888,
                (char*)&lK[0][0] + i * 8192 + (w << 10));
  __builtin_amdgcn_sched_barrier(0);
  if (t < 192) {
#pragma unroll
    for (int i = 0; i < 8; ++i) {             // compiler waits vrow's vmcnt
      int cs = (c8s * 8 + i) ^ (k4s & 15);
      u16x4 q;
#pragma unroll
      for (int kr = 0; kr < 4; ++kr) q[kr] = vrow[kr][i];
      *(u16x4*)(&lV[0][(k4s * 97 + cs) * 4]) = q;
    }
#pragma unroll
    for (int kr = 0; kr < 4; ++kr)            // V(1) issue
      vrow[kr] = *(const u16x8*)(pVb + (size_t)(64 + kr * 4) * 5888 / 4 * 4);
  }
  // NOTE: V(1) address = pVb + 64*5888 + kr*5888 (rows kb0+k4s*4+kr)
  // rewritten explicitly below to avoid the accidental expression above
  if (t < 192) {
    const ushort_t* pV1 = pVb + (size_t)64 * 5888;
#pragma unroll
    for (int kr = 0; kr < 4; ++kr)
      vrow[kr] = *(const u16x8*)(pV1 + (size_t)kr * 5888);
  }
  __builtin_amdgcn_sched_barrier(0);
  if (w < 3)
    asm volatile("s_waitcnt vmcnt(4) lgkmcnt(0)" ::: "memory");
  else
    asm volatile("s_waitcnt vmcnt(0) lgkmcnt(0)" ::: "memory");
  __builtin_amdgcn_s_barrier();
  asm volatile("" ::: "memory");
  __builtin_amdgcn_sched_barrier(0);

  for (int kt = 0; kt < nkt; ++kt) {
    const int kb0 = kt * 64;
    const int cur = kt & 1, nxt = cur ^ 1;
    const bool pre1 = (kt + 1 < nkt), pre2 = (kt + 2 < nkt);
    // ---- K(kt+1) -> bufK[nxt] ----
    if (pre1) {
      const ushort_t* pK = pKb + (size_t)(kb0 + 64) * 5888;
#pragma unroll
      for (int i = 0; i < 2; ++i)
        gload_lds16(pK + (size_t)i * 32 * 5888,
                    (char*)&lK[nxt][0] + i * 8192 + (w << 10));
    }
    __builtin_amdgcn_sched_barrier(0);
    // ---- V(kt+1): regs -> bufV[nxt]; then issue V(kt+2) ----
    if (pre1 && t < 192) {
#pragma unroll
      for (int i = 0; i < 8; ++i) {           // compiler waits vrow's vmcnt
        int cs = (c8s * 8 + i) ^ (k4s & 15);
        u16x4 q;
#pragma unroll
        for (int kr = 0; kr < 4; ++kr) q[kr] = vrow[kr][i];
        *(u16x4*)(&lV[nxt][(k4s * 97 + cs) * 4]) = q;
      }
      if (pre2) {
        const ushort_t* pV = pVb + (size_t)(kb0 + 128) * 5888;
#pragma unroll
        for (int kr = 0; kr < 4; ++kr)
          vrow[kr] = *(const u16x8*)(pV + (size_t)kr * 5888);
      }
    }
    __builtin_amdgcn_sched_barrier(0);
    // ---- compute(cur) ----
    if (kb0 <= q0 + 31) {
      f32x4 s[4][2] = {};
      __builtin_amdgcn_s_setprio(1);
#pragma unroll
      for (int cb = 0; cb < 4; ++cb) {
        const int kv = cb * 16 + fr;
        bf16x8 kf[4];
#pragma unroll
        for (int kb = 0; kb < 4; ++kb)
          kf[kb] = *(const bf16x8*)((const char*)&lK[cur][0] + kv * 256 +
                                    ((kb * 64 + fg * 16) ^ ((kv & 7) << 4)));
#pragma unroll
        for (int rq = 0; rq < 2; ++rq)
#pragma unroll
          for (int kb = 0; kb < 4; ++kb)
            s[cb][rq] = __builtin_amdgcn_mfma_f32_16x16x32_bf16(
                kf[kb], qf[rq][kb], s[cb][rq], 0, 0, 0);
      }
      __builtin_amdgcn_s_setprio(0);
      if (kb0 + 63 > q0) {
#pragma unroll
        for (int rq = 0; rq < 2; ++rq) {
          const int qrel = q0 + rq * 16 + fr - kb0;
#pragma unroll
          for (int cb = 0; cb < 4; ++cb)
#pragma unroll
            for (int j = 0; j < 4; ++j)
              if (cb * 16 + fg * 4 + j > qrel) s[cb][rq][j] = -3.0e38f;
        }
      }
      s16x4 pb[4][2];
#pragma unroll
      for (int rq = 0; rq < 2; ++rq) {
        f32x4 ps4 = {};
#pragma unroll
        for (int cb = 0; cb < 4; ++cb) {
#pragma unroll
          for (int j = 0; j < 4; ++j) {
            float p = exp2f(fmaf(s[cb][rq][j], scl2e, -MB));
            s[cb][rq][j] = p;
            ps4[j] += p;
          }
        }
        lreg[rq] += (ps4[0] + ps4[1]) + (ps4[2] + ps4[3]);
#pragma unroll
        for (int cb = 0; cb < 4; ++cb) {
          s16x4 v;
#pragma unroll
          for (int j = 0; j < 4; ++j) v[j] = f2bf_n(s[cb][rq][j]);
          pb[cb][rq] = v;
        }
      }
      __builtin_amdgcn_s_setprio(1);
#pragma unroll
      for (int cb = 0; cb < 4; ++cb) {
        const int k4 = cb * 4 + fg;
        s16x4 va[6];
#pragma unroll
        for (int c6 = 0; c6 < 6; ++c6)
          va[c6] = *(const s16x4*)(
              &lV[cur][(k4 * 97 + (((c6 * 16 + fr) ^ (k4 & 15)))) * 4]);
#pragma unroll
        for (int c6 = 0; c6 < 6; ++c6)
#pragma unroll
          for (int rq = 0; rq < 2; ++rq)
            oacc[c6][rq] = __builtin_amdgcn_mfma_f32_16x16x16bf16_1k(
                va[c6], pb[cb][rq], oacc[c6][rq], 0, 0, 0);
      }
      __builtin_amdgcn_s_setprio(0);
    }
    // ---- tail barrier: K(kt+1) drained; V(kt+2) stays in flight ----
    if (pre1) {
      __builtin_amdgcn_sched_barrier(0);
      if (pre2 && w < 3)
        asm volatile("s_waitcnt vmcnt(4) lgkmcnt(0)" ::: "memory");
      else
        asm volatile("s_waitcnt vmcnt(0) lgkmcnt(0)" ::: "memory");
      __builtin_amdgcn_s_barrier();
      asm volatile("" ::: "memory");
      __builtin_amdgcn_sched_barrier(0);
    }
  }
  // ---- epilogue: deferred l reduction, then divide ----
#pragma unroll
  for (int rq = 0; rq < 2; ++rq) {
    float l = lreg[rq];
    l += __shfl_xor(l, 16, 64);
    l += __shfl_xor(l, 32, 64);
    const float inv = 1.0f / l;
    const size_t rowb = (size_t)(tb + q0 + rq * 16 + fr) * 3072 + h * 96;
#pragma unroll
    for (int c6 = 0; c6 < 6; ++c6) {
      u16x4 o;
#pragma unroll
      for (int j = 0; j < 4; ++j)
        o[j] = (unsigned short)f2bf_n(oacc[c6][rq][j] * inv);
      *(u16x4*)(&O[rowb + c6 * 16 + fg * 4]) = o;
    }
  }
}

// ---------------- launcher ----------------
extern "C" void kernel_launch(void* const* d_in, const int* in_sizes, int n_in,
                              void* d_out, int out_size, void* d_ws,
                              size_t ws_size, hipStream_t stream) {
  const float* X  = (const float*)d_in[0];
  const int*   pos = (const int*)d_in[1];
  const float* Wq = (const float*)d_in[2];
  const float* Wk = (const float*)d_in[3];
  const float* Wv = (const float*)d_in[4];
  const float* Wo = (const float*)d_in[5];
  float* out = (float*)d_out;

  ushort_t* Xb    = (ushort_t*)d_ws;
  ushort_t* Wob   = Xb + 16777216;
  ushort_t* QKV   = Wob + 12582912;
  ushort_t* AO    = QKV + 24117248;
  ushort_t* Wqkvb = (ushort_t*)d_out;   // staged, consumed before O-proj

  // one fused conversion dispatch: X, Wq, Wk, Wv, Wo
  k_xw_to_bf16<<<26112, 256, 0, stream>>>(X, Wq, Wk, Wv, Wo, Xb, Wqkvb,
                                          Wqkvb + 16777216,
                                          Wqkvb + 20971520, Wob);

  // QKV projection + fused RoPE: (4096x4096)*(5888x4096)^T -> (4096x5888)
  k_gemm_bt<1, 1><<<dim3(32, 46), 256, 0, stream>>>(Xb, Wqkvb, QKV, 4096,
                                                    4096, 4096, 5888, pos);
  // causal GQA flash attention -> (4096 x 3072) bf16
  k_attn<<<dim3(8, 32, 2), 512, 0, stream>>>(QKV, AO);
  // output projection: (4096 x 3072) * (4096 x 3072)^T -> (4096 x 4096) f32
  k_gemm_bt<0, 0><<<dim3(32, 32), 256, 0, stream>>>(AO, Wob, out, 3072, 3072,
                                                    3072, 4096, nullptr);
}

// Round 20
// 438.203 us; speedup vs baseline: 1.0525x; 1.0525x over previous
//
#include <hip/hip_runtime.h>

typedef __attribute__((ext_vector_type(4))) float f32x4;
typedef __attribute__((ext_vector_type(8))) __bf16 bf16x8;
typedef __attribute__((ext_vector_type(8))) unsigned short u16x8;
typedef __attribute__((ext_vector_type(4))) unsigned short u16x4;
typedef __attribute__((ext_vector_type(4))) short s16x4;
typedef unsigned short ushort_t;

// ---------- bf16 helpers ----------
__device__ __forceinline__ unsigned short f2bf(float x) {
  unsigned u = __builtin_bit_cast(unsigned, x);
  u += 0x7fffu + ((u >> 16) & 1u);
  return (unsigned short)(u >> 16);
}
__device__ __forceinline__ float bf2f(unsigned short h) {
  unsigned u = ((unsigned)h) << 16;
  return __builtin_bit_cast(float, u);
}
__device__ __forceinline__ short f2bf_n(float x) {
  return __builtin_bit_cast(short, (__bf16)x);
}

// ---------- async global->LDS (16B per lane) ----------
__device__ __forceinline__ void gload_lds16(const void* g, void* l) {
  __builtin_amdgcn_global_load_lds(
      (const __attribute__((address_space(1))) unsigned int*)g,
      (__attribute__((address_space(3))) unsigned int*)l, 16, 0, 0);
}

// ---------- fused all-weights+X f32->bf16 (one dispatch, exact ranges) ----------
// blocks: [0,8192) X | [8192,16384) Wq | [16384,18432) Wk | [18432,19968) Wv
//         | [19968,26112) Wo.  All ranges exact multiples of 256 thr x 8 elem.
__global__ __launch_bounds__(256) void k_xw_to_bf16(
    const float* __restrict__ X, const float* __restrict__ Wq,
    const float* __restrict__ Wk, const float* __restrict__ Wv,
    const float* __restrict__ Wo,
    ushort_t* __restrict__ dX, ushort_t* __restrict__ dWq,
    ushort_t* __restrict__ dWk, ushort_t* __restrict__ dWv,
    ushort_t* __restrict__ dWo) {
  const int b = blockIdx.x;
  const float* src;
  ushort_t* dst;
  int i;
  if (b < 8192)       { src = X;  dst = dX;  i = b * 256 + threadIdx.x; }
  else if (b < 16384) { src = Wq; dst = dWq; i = (b - 8192) * 256 + threadIdx.x; }
  else if (b < 18432) { src = Wk; dst = dWk; i = (b - 16384) * 256 + threadIdx.x; }
  else if (b < 19968) { src = Wv; dst = dWv; i = (b - 18432) * 256 + threadIdx.x; }
  else                { src = Wo; dst = dWo; i = (b - 19968) * 256 + threadIdx.x; }
  float4 a = ((const float4*)src)[i * 2 + 0];
  float4 c = ((const float4*)src)[i * 2 + 1];
  u16x8 o;
  o[0] = f2bf(a.x); o[1] = f2bf(a.y); o[2] = f2bf(a.z); o[3] = f2bf(a.w);
  o[4] = f2bf(c.x); o[5] = f2bf(c.y); o[6] = f2bf(c.z); o[7] = f2bf(c.w);
  ((u16x8*)dst)[i] = o;
}

// ---------- bf16 B^T GEMM: C[M,N] = A[M,K] * B[N,K]^T (m97 structure) ----------
// launch_bounds (256,4): R14 verified VGPR 68->64, occupancy 31%, MfmaUtil 48.
// ROPE=1 (QKV): rotary fused in epilogue.
template <int OUT_BF16, int ROPE>
__global__ __launch_bounds__(256, 4) void k_gemm_bt(
    const ushort_t* __restrict__ A, const ushort_t* __restrict__ B,
    void* __restrict__ C, int K, int lda, int ldb, int ldc,
    const int* __restrict__ pos_ids) {
  __shared__ ushort_t lA[128 * 64];
  __shared__ ushort_t lB[128 * 64];
  const int t = threadIdx.x;
  const int ln = t & 63, w = t >> 6;
  const int fr = ln & 15, fg = ln >> 4;
  const int m0 = blockIdx.x * 128, n0 = blockIdx.y * 128;
  const int wr = (w >> 1) * 64, wc = (w & 1) * 64;

  const int srow = t >> 3;
  const int scol = ((((t & 7) * 16) ^ ((srow & 7) << 4)) >> 1);
  const ushort_t* pA = A + (srow + m0) * lda + scol;
  const ushort_t* pB = B + (srow + n0) * ldb + scol;
  char* lAb = (char*)lA + (w << 10);
  char* lBb = (char*)lB + (w << 10);

  f32x4 acc[4][4] = {};

  for (int k0 = 0; k0 < K; k0 += 64) {
    __syncthreads();
#pragma unroll
    for (int i = 0; i < 4; ++i) {
      gload_lds16(pA + i * 32 * lda + k0, lAb + i * 4096);
      gload_lds16(pB + i * 32 * ldb + k0, lBb + i * 4096);
    }
    __syncthreads();
#pragma unroll
    for (int kh = 0; kh < 2; ++kh) {
      bf16x8 af[4], bfv[4];
#pragma unroll
      for (int m = 0; m < 4; ++m) {
        int row = wr + m * 16 + fr;
        af[m] = *(const bf16x8*)((const char*)lA + row * 128 +
                                 ((kh * 64 + fg * 16) ^ ((row & 7) << 4)));
      }
#pragma unroll
      for (int n = 0; n < 4; ++n) {
        int row = wc + n * 16 + fr;
        bfv[n] = *(const bf16x8*)((const char*)lB + row * 128 +
                                  ((kh * 64 + fg * 16) ^ ((row & 7) << 4)));
      }
#pragma unroll
      for (int m = 0; m < 4; ++m)
#pragma unroll
        for (int n = 0; n < 4; ++n)
          acc[m][n] = __builtin_amdgcn_mfma_f32_16x16x32_bf16(
              af[m], bfv[n], acc[m][n], 0, 0, 0);
    }
  }

  // ---- fused RoPE (QKV epilogue only; wave-uniform predicate) ----
  if (ROPE) {
    if (n0 < 5120 && wc == 0) {
#pragma unroll
      for (int n = 0; n < 2; ++n) {
        const float fi = (float)(n * 16 + fr);          // freq index 0..31
        const float inv = exp2f(-fi * (13.287712379549449f / 32.0f));
#pragma unroll
        for (int m = 0; m < 4; ++m) {
          const int row = m0 + wr + m * 16 + fg * 4;
#pragma unroll
          for (int j = 0; j < 4; ++j) {
            const float ang = (float)pos_ids[row + j] * inv;
            float sn, cs;
            __sincosf(ang, &sn, &cs);
            const float x1 = acc[m][n][j], x2 = acc[m][n + 2][j];
            acc[m][n][j]     = x1 * cs - x2 * sn;
            acc[m][n + 2][j] = x2 * cs + x1 * sn;
          }
        }
      }
    }
  }

#pragma unroll
  for (int m = 0; m < 4; ++m)
#pragma unroll
    for (int n = 0; n < 4; ++n) {
      int row = m0 + wr + m * 16 + fg * 4;
      int col = n0 + wc + n * 16 + fr;
#pragma unroll
      for (int j = 0; j < 4; ++j) {
        if (OUT_BF16)
          ((ushort_t*)C)[(size_t)(row + j) * ldc + col] = f2bf(acc[m][n][j]);
        else
          ((float*)C)[(size_t)(row + j) * ldc + col] = acc[m][n][j];
      }
    }
}

// ---------- causal GQA flash attention (S^T / O^T, reg-resident P) ----------
// KVBLK=128 staging, two 64-wide compute halves. Fixed-shift softmax (exact).
// lV rows padded to 100 slots (R17: bank-conflict fix). l cross-lane reduce
// DEFERRED to epilogue. R19 lesson: KVBLK=64 K/V double-buffer regressed
// (+22us) — barrier count dominates over prefetch depth at this occupancy;
// this KVBLK=128 single-buffer form is the measured optimum (439us total).
__global__ __launch_bounds__(512, 2) void k_attn(
    const ushort_t* __restrict__ QKV, ushort_t* __restrict__ O) {
  __shared__ ushort_t lK[128 * 128];     // XOR-swizzled rows of 256B
  __shared__ ushort_t lV[32 * 100 * 4];  // quad layout, padded row stride

  const int t = threadIdx.x, ln = t & 63, w = t >> 6;
  const int fr = ln & 15, fg = ln >> 4;
  const int h = blockIdx.y, b = blockIdx.z;
  const int qt = b ? (7 - (int)blockIdx.x) : (int)blockIdx.x;
  const int hk = h >> 2;
  const int q0 = qt * 256 + w * 32;
  const int tb = b * 2048;

  // Q B-frags: lane (fr,fg) holds Q[q0+rq*16+fr][kb*32+fg*8 ..+7]
  bf16x8 qf[2][4];
#pragma unroll
  for (int rq = 0; rq < 2; ++rq)
#pragma unroll
    for (int kb = 0; kb < 4; ++kb)
      qf[rq][kb] = *(const bf16x8*)(QKV +
                    (size_t)(tb + q0 + rq * 16 + fr) * 5888 + h * 128 +
                    kb * 32 + fg * 8);

  f32x4 oacc[6][2] = {};            // O^T: c = c6*16+fg*4+j, q = rq*16+fr
  float lreg[2] = {0.f, 0.f};       // per-lane partial of l (reduced at end)

  const int krow = t >> 4;                    // 0..31 (4 issues x 32 rows)
  const int kse = ((((t & 15) * 16) ^ (((t >> 4) & 7) << 4)) >> 1);
  const int k4s = t / 12, c8s = t % 12;       // V staging unit (t<384)

  const float sc = 0.088388347648318447f;     // 1/sqrt(128)
  const float l2e = 1.4426950408889634f;
  const float scl2e = sc * l2e;
  const float MB = 16.0f * l2e;               // fixed softmax shift (exact)

  // ---- initial V prefetch (tile 0: 128 k-rows) ----
  u16x8 vrow[4];
  const ushort_t* pVb =
      QKV + (size_t)(tb + k4s * 4) * 5888 + 5120 + hk * 96 + c8s * 8;
  if (t < 384) {
#pragma unroll
    for (int kr = 0; kr < 4; ++kr)
      vrow[kr] = *(const u16x8*)(pVb + (size_t)kr * 5888);
  }

  const int nkt = (qt + 1) * 2;               // 128-wide tiles
  for (int kt = 0; kt < nkt; ++kt) {
    const int kb0t = kt * 128;
    __syncthreads();
    // ---- V(kt): regs -> quad-layout LDS (padded rows) ----
    if (t < 384) {
#pragma unroll
      for (int i = 0; i < 8; ++i) {
        int cs = (c8s * 8 + i) ^ (k4s & 15);
        u16x4 q;
#pragma unroll
        for (int kr = 0; kr < 4; ++kr) q[kr] = vrow[kr][i];
        *(u16x4*)(&lV[(k4s * 100 + cs) * 4]) = q;
      }
    }
    // ---- K(kt): async gload -> lK (swizzled); 4 issues x 32 rows ----
    {
      const ushort_t* pK =
          QKV + (size_t)(tb + kb0t + krow) * 5888 + 4096 + hk * 128 + kse;
#pragma unroll
      for (int i = 0; i < 4; ++i)
        gload_lds16(pK + (size_t)i * 32 * 5888,
                    (char*)lK + i * 8192 + (w << 10));
    }
    __builtin_amdgcn_sched_barrier(0);   // pin: K issues older than V issues
    // ---- V(kt+1) prefetch issue ----
    const bool pre = (kt + 1 < nkt);
    if (pre && t < 384) {
      const ushort_t* pV = pVb + (size_t)(kb0t + 128) * 5888;
#pragma unroll
      for (int kr = 0; kr < 4; ++kr)
        vrow[kr] = *(const u16x8*)(pV + (size_t)kr * 5888);
    }
    __builtin_amdgcn_sched_barrier(0);   // pin: V issues before the wait
    // ---- staging barrier: counted vmcnt keeps V(kt+1) in flight ----
    if (pre && w < 6)
      asm volatile("s_waitcnt vmcnt(4) lgkmcnt(0)" ::: "memory");
    else
      asm volatile("s_waitcnt vmcnt(0) lgkmcnt(0)" ::: "memory");
    __builtin_amdgcn_s_barrier();
    asm volatile("" ::: "memory");
    __builtin_amdgcn_sched_barrier(0);

    // ---- two 64-wide compute halves, no barrier between ----
#pragma unroll
    for (int h64 = 0; h64 < 2; ++h64) {
      const int kb0 = kb0t + h64 * 64;
      if (kb0 > q0 + 31) break;   // later halves masked too
      // ---- S^T = K Q^T ----
      f32x4 s[4][2] = {};
      __builtin_amdgcn_s_setprio(1);
#pragma unroll
      for (int cb = 0; cb < 4; ++cb) {
        const int kv = h64 * 64 + cb * 16 + fr;
        bf16x8 kf[4];
#pragma unroll
        for (int kb = 0; kb < 4; ++kb)
          kf[kb] = *(const bf16x8*)((const char*)lK + kv * 256 +
                                    ((kb * 64 + fg * 16) ^ ((kv & 7) << 4)));
#pragma unroll
        for (int rq = 0; rq < 2; ++rq)
#pragma unroll
          for (int kb = 0; kb < 4; ++kb)
            s[cb][rq] = __builtin_amdgcn_mfma_f32_16x16x32_bf16(
                kf[kb], qf[rq][kb], s[cb][rq], 0, 0, 0);
      }
      __builtin_amdgcn_s_setprio(0);
      // ---- mask (only partial halves; wave-uniform branch) ----
      if (kb0 + 63 > q0) {
#pragma unroll
        for (int rq = 0; rq < 2; ++rq) {
          const int qrel = q0 + rq * 16 + fr - kb0;
#pragma unroll
          for (int cb = 0; cb < 4; ++cb)
#pragma unroll
            for (int j = 0; j < 4; ++j)
              if (cb * 16 + fg * 4 + j > qrel) s[cb][rq][j] = -3.0e38f;
        }
      }
      // ---- fixed-shift softmax: p = exp2(s*sc*l2e - 16*l2e) ----
      s16x4 pb[4][2];
#pragma unroll
      for (int rq = 0; rq < 2; ++rq) {
        f32x4 ps4 = {};
#pragma unroll
        for (int cb = 0; cb < 4; ++cb) {
#pragma unroll
          for (int j = 0; j < 4; ++j) {
            float p = exp2f(fmaf(s[cb][rq][j], scl2e, -MB));
            s[cb][rq][j] = p;
            ps4[j] += p;
          }
        }
        lreg[rq] += (ps4[0] + ps4[1]) + (ps4[2] + ps4[3]);  // no shfl here
#pragma unroll
        for (int cb = 0; cb < 4; ++cb) {
          s16x4 v;
#pragma unroll
          for (int j = 0; j < 4; ++j) v[j] = f2bf_n(s[cb][rq][j]);
          pb[cb][rq] = v;
        }
      }
      // ---- O^T += V^T P ----
      __builtin_amdgcn_s_setprio(1);
#pragma unroll
      for (int cb = 0; cb < 4; ++cb) {
        const int k4 = h64 * 16 + cb * 4 + fg;
        s16x4 va[6];
#pragma unroll
        for (int c6 = 0; c6 < 6; ++c6)
          va[c6] = *(const s16x4*)(
              &lV[((k4 * 100 + (((c6 * 16 + fr) ^ (k4 & 15))))) * 4]);
#pragma unroll
        for (int c6 = 0; c6 < 6; ++c6)
#pragma unroll
          for (int rq = 0; rq < 2; ++rq)
            oacc[c6][rq] = __builtin_amdgcn_mfma_f32_16x16x16bf16_1k(
                va[c6], pb[cb][rq], oacc[c6][rq], 0, 0, 0);
      }
      __builtin_amdgcn_s_setprio(0);
    }
  }
  // ---- epilogue: deferred l reduction (linear in tiles), then divide ----
#pragma unroll
  for (int rq = 0; rq < 2; ++rq) {
    float l = lreg[rq];
    l += __shfl_xor(l, 16, 64);
    l += __shfl_xor(l, 32, 64);
    const float inv = 1.0f / l;
    const size_t rowb = (size_t)(tb + q0 + rq * 16 + fr) * 3072 + h * 96;
#pragma unroll
    for (int c6 = 0; c6 < 6; ++c6) {
      u16x4 o;
#pragma unroll
      for (int j = 0; j < 4; ++j)
        o[j] = (unsigned short)f2bf_n(oacc[c6][rq][j] * inv);
      *(u16x4*)(&O[rowb + c6 * 16 + fg * 4]) = o;
    }
  }
}

// ---------------- launcher ----------------
extern "C" void kernel_launch(void* const* d_in, const int* in_sizes, int n_in,
                              void* d_out, int out_size, void* d_ws,
                              size_t ws_size, hipStream_t stream) {
  const float* X  = (const float*)d_in[0];
  const int*   pos = (const int*)d_in[1];
  const float* Wq = (const float*)d_in[2];
  const float* Wk = (const float*)d_in[3];
  const float* Wv = (const float*)d_in[4];
  const float* Wo = (const float*)d_in[5];
  float* out = (float*)d_out;

  ushort_t* Xb    = (ushort_t*)d_ws;
  ushort_t* Wob   = Xb + 16777216;
  ushort_t* QKV   = Wob + 12582912;
  ushort_t* AO    = QKV + 24117248;
  ushort_t* Wqkvb = (ushort_t*)d_out;   // staged, consumed before O-proj

  // one fused conversion dispatch: X, Wq, Wk, Wv, Wo
  k_xw_to_bf16<<<26112, 256, 0, stream>>>(X, Wq, Wk, Wv, Wo, Xb, Wqkvb,
                                          Wqkvb + 16777216,
                                          Wqkvb + 20971520, Wob);

  // QKV projection + fused RoPE: (4096x4096)*(5888x4096)^T -> (4096x5888)
  k_gemm_bt<1, 1><<<dim3(32, 46), 256, 0, stream>>>(Xb, Wqkvb, QKV, 4096,
                                                    4096, 4096, 5888, pos);
  // causal GQA flash attention -> (4096 x 3072) bf16
  k_attn<<<dim3(8, 32, 2), 512, 0, stream>>>(QKV, AO);
  // output projection: (4096 x 3072) * (4096 x 3072)^T -> (4096 x 4096) f32
  k_gemm_bt<0, 0><<<dim3(32, 32), 256, 0, stream>>>(AO, Wob, out, 3072, 3072,
                                                    3072, 4096, nullptr);
}